// Round 4
// baseline (1974.755 us; speedup 1.0000x reference)
//
#include <hip/hip_runtime.h>

#define NNODES 20000
#define NEDGES 320000
#define NB 16
#define FIN 256
#define NP 5
#define NA 5

// ---------------------------------------------------------------------------
// degree: deg[b*N+dst] += w  (then +1 self loop in finalize)
// ---------------------------------------------------------------------------
__global__ __launch_bounds__(256) void deg_atomic_kernel(
    const int* __restrict__ ei, const float* __restrict__ ew,
    float* __restrict__ deg) {
  int b = blockIdx.y;
  int e = blockIdx.x * 256 + threadIdx.x;
  if (e < NEDGES) {
    int dst = ei[b * 2 * NEDGES + NEDGES + e];
    float w = ew[b * NEDGES + e];
    atomicAdd(&deg[b * NNODES + dst], w);
  }
}

__global__ __launch_bounds__(256) void deg_final_kernel(
    float* __restrict__ deg, float* __restrict__ dis, float* __restrict__ inv) {
  int i = blockIdx.x * 256 + threadIdx.x;
  if (i < NB * NNODES) {
    float d = deg[i] + 1.0f;
    float r = rsqrtf(d);
    deg[i] = d;
    dis[i] = r;
    inv[i] = 1.0f / d;
  }
}

// ---------------------------------------------------------------------------
// butterfly reduction: p[16] per lane -> returns sum over 64 lanes of p[.][j]
// with j = lane & 15 (all static indices; cndmask selects, 17 shfl total)
// ---------------------------------------------------------------------------
__device__ __forceinline__ float wave_reduce16(const float p[16], int lane) {
  float v8[8];
  {
    const bool hi = lane & 1;
#pragma unroll
    for (int q = 0; q < 8; ++q) {
      float keep = hi ? p[2 * q + 1] : p[2 * q];
      float give = hi ? p[2 * q] : p[2 * q + 1];
      v8[q] = keep + __shfl_xor(give, 1);
    }
  }
  float v4[4];
  {
    const bool hi = (lane >> 1) & 1;
#pragma unroll
    for (int q = 0; q < 4; ++q) {
      float keep = hi ? v8[2 * q + 1] : v8[2 * q];
      float give = hi ? v8[2 * q] : v8[2 * q + 1];
      v4[q] = keep + __shfl_xor(give, 2);
    }
  }
  float v2[2];
  {
    const bool hi = (lane >> 2) & 1;
#pragma unroll
    for (int q = 0; q < 2; ++q) {
      float keep = hi ? v2[0] * 0.0f + (hi ? v4[2 * q + 1] : v4[2 * q]) : v4[2 * q];
      // (see below — replaced; keep simple form)
      keep = hi ? v4[2 * q + 1] : v4[2 * q];
      float give = hi ? v4[2 * q] : v4[2 * q + 1];
      v2[q] = keep + __shfl_xor(give, 4);
    }
  }
  float v1;
  {
    const bool hi = (lane >> 3) & 1;
    float keep = hi ? v2[1] : v2[0];
    float give = hi ? v2[0] : v2[1];
    v1 = keep + __shfl_xor(give, 8);
  }
  v1 += __shfl_xor(v1, 16);
  v1 += __shfl_xor(v1, 32);
  return v1;
}

// ---------------------------------------------------------------------------
// layer-1 matmul: xw[row][0..15] = x[row][0..255] @ W1, one wave per row,
// W1 held in 64 VGPRs per lane (lane covers k = lane*4 .. lane*4+3)
// ---------------------------------------------------------------------------
__global__ __launch_bounds__(256) void mm1_kernel(
    const float* __restrict__ x, const float* __restrict__ W1,
    float* __restrict__ xw) {
  const int lane = threadIdx.x & 63;
  const int wib = threadIdx.x >> 6;
  const int wave = blockIdx.x * 4 + wib;
  const int nwaves = gridDim.x * 4;

  // wreg[t*16+j] = W1[(lane*4+t)*16 + j]  (contiguous 256B per lane)
  float wreg[64];
  {
    const float4* W4 = (const float4*)(W1 + lane * 64);
#pragma unroll
    for (int q = 0; q < 16; ++q) {
      float4 v = W4[q];
      wreg[q * 4 + 0] = v.x;
      wreg[q * 4 + 1] = v.y;
      wreg[q * 4 + 2] = v.z;
      wreg[q * 4 + 3] = v.w;
    }
  }
  const int nrows = NB * NNODES;
  for (int row = wave; row < nrows; row += nwaves) {
    float4 xv = ((const float4*)x)[(long long)row * 64 + lane];
    float p[16];
#pragma unroll
    for (int j = 0; j < 16; ++j) {
      p[j] = xv.x * wreg[j] + xv.y * wreg[16 + j] + xv.z * wreg[32 + j] +
             xv.w * wreg[48 + j];
    }
    float v = wave_reduce16(p, lane);
    if (lane < 16) xw[(long long)row * 16 + lane] = v;
  }
}

// ---------------------------------------------------------------------------
// small matmul for layers 2/3: out[row][j] = h[row][0..15] @ W[16][FOUT]
// ---------------------------------------------------------------------------
template <int FOUT>
__global__ __launch_bounds__(256) void mm_small_kernel(
    const float* __restrict__ h, const float* __restrict__ W,
    float* __restrict__ out) {
  __shared__ float Ws[16 * FOUT];
  for (int t = threadIdx.x; t < 16 * FOUT; t += 256) Ws[t] = W[t];
  __syncthreads();
  int idx = blockIdx.x * 256 + threadIdx.x;
  if (idx >= NB * NNODES * FOUT) return;
  int row = idx / FOUT;
  int j = idx & (FOUT - 1);
  const float4* hr = (const float4*)(h + (long long)row * 16);
  float hv[16];
#pragma unroll
  for (int q = 0; q < 4; ++q) {
    float4 v = hr[q];
    hv[q * 4 + 0] = v.x;
    hv[q * 4 + 1] = v.y;
    hv[q * 4 + 2] = v.z;
    hv[q * 4 + 3] = v.w;
  }
  float acc = 0.0f;
#pragma unroll
  for (int k = 0; k < 16; ++k) acc += hv[k] * Ws[k * FOUT + j];
  out[idx] = acc;
}

// ---------------------------------------------------------------------------
// edge scatter: agg[dst][j] += xw[src][j] * dis[src]*w*dis[dst]
// ---------------------------------------------------------------------------
template <int F>
__global__ __launch_bounds__(256) void edge_agg_kernel(
    const int* __restrict__ ei, const float* __restrict__ ew,
    const float* __restrict__ dis, const float* __restrict__ xw,
    float* __restrict__ agg) {
  int b = blockIdx.y;
  int idx = blockIdx.x * 256 + threadIdx.x;
  if (idx >= NEDGES * F) return;
  int e = idx / F;  // F is power of two -> shift
  int j = idx & (F - 1);
  const int* eib = ei + b * 2 * NEDGES;
  int src = eib[e];
  int dst = eib[NEDGES + e];
  float w = ew[b * NEDGES + e];
  float norm = dis[b * NNODES + src] * w * dis[b * NNODES + dst];
  float val = xw[((long long)b * NNODES + src) * F + j] * norm;
  atomicAdd(&agg[((long long)b * NNODES + dst) * F + j], val);
}

// ---------------------------------------------------------------------------
// combine: out = maybe_tanh(agg + xw * inv_deg + bias)   (in-place on agg ok)
// ---------------------------------------------------------------------------
template <int F, bool TANH>
__global__ __launch_bounds__(256) void combine_kernel(
    const float* __restrict__ agg, const float* __restrict__ xw,
    const float* __restrict__ inv, const float* __restrict__ bias,
    float* __restrict__ out) {
  long long i = (long long)blockIdx.x * 256 + threadIdx.x;
  if (i >= (long long)NB * NNODES * F) return;
  int j = (int)(i & (F - 1));
  long long n = i / F;
  float v = agg[i] + xw[i] * inv[n] + bias[j];
  out[i] = TANH ? tanhf(v) : v;
}

// ---------------------------------------------------------------------------
// gather + 3-layer MLP head, one block per batch element
// ---------------------------------------------------------------------------
__global__ __launch_bounds__(256) void fc_kernel(
    const float* __restrict__ emb, const int* __restrict__ pos,
    const float* __restrict__ fcW1, const float* __restrict__ fcb1,
    const float* __restrict__ fcW2, const float* __restrict__ fcb2,
    const float* __restrict__ fcW3, const float* __restrict__ fcb3,
    float* __restrict__ out) {
  int b = blockIdx.x;
  int tid = threadIdx.x;
  __shared__ float flat[160];
  __shared__ float hb[128];
  if (tid < 160) {
    int p = tid / 32, j = tid & 31;
    int pv = pos[b * NP + p];
    float v;
    if (pv == -1) {
      v = -3.0f;  // -DEPTH
    } else {
      int node = pv < 0 ? 0 : (pv > NNODES - 1 ? NNODES - 1 : pv);
      v = emb[((long long)b * NNODES + node) * 32 + j];
    }
    flat[tid] = v;
  }
  __syncthreads();
  float acc1 = 0.0f;
  if (tid < 128) {
    acc1 = fcb1[tid];
#pragma unroll 8
    for (int k = 0; k < 160; ++k) acc1 += flat[k] * fcW1[k * 128 + tid];
    acc1 = tanhf(acc1);
  }
  __syncthreads();
  if (tid < 128) hb[tid] = acc1;
  __syncthreads();
  float acc2 = 0.0f;
  if (tid < 128) {
    acc2 = fcb2[tid];
#pragma unroll 8
    for (int k = 0; k < 128; ++k) acc2 += hb[k] * fcW2[k * 128 + tid];
    acc2 = tanhf(acc2);
  }
  __syncthreads();
  if (tid < 128) flat[tid] = acc2;
  __syncthreads();
  if (tid < NA) {
    float acc = fcb3[tid];
#pragma unroll 8
    for (int k = 0; k < 128; ++k) acc += flat[k] * fcW3[k * NA + tid];
    out[b * NA + tid] = acc;
  }
}

// ---------------------------------------------------------------------------
extern "C" void kernel_launch(void* const* d_in, const int* in_sizes, int n_in,
                              void* d_out, int out_size, void* d_ws,
                              size_t ws_size, hipStream_t stream) {
  const float* x = (const float*)d_in[0];
  const int* ei = (const int*)d_in[1];
  const float* ew = (const float*)d_in[2];
  const int* pos = (const int*)d_in[3];
  const float* W1 = (const float*)d_in[4];
  const float* b1 = (const float*)d_in[5];
  const float* W2 = (const float*)d_in[6];
  const float* b2 = (const float*)d_in[7];
  const float* W3 = (const float*)d_in[8];
  const float* b3 = (const float*)d_in[9];
  const float* fcW1 = (const float*)d_in[10];
  const float* fcb1 = (const float*)d_in[11];
  const float* fcW2 = (const float*)d_in[12];
  const float* fcb2 = (const float*)d_in[13];
  const float* fcW3 = (const float*)d_in[14];
  const float* fcb3 = (const float*)d_in[15];
  float* out = (float*)d_out;

  float* ws = (float*)d_ws;
  const long long BN = (long long)NB * NNODES;  // 320000
  float* deg = ws;               // BN
  float* dis = ws + BN;          // BN
  float* inv = ws + 2 * BN;      // BN
  float* bufA = ws + 3 * BN;     // BN*32
  float* bufB = bufA + BN * 32;  // BN*32
  // total ws use: 67*BN*4 B = 85.8 MB

  // degree (reused by all 3 layers)
  hipMemsetAsync(deg, 0, BN * sizeof(float), stream);
  deg_atomic_kernel<<<dim3((NEDGES + 255) / 256, NB), 256, 0, stream>>>(ei, ew,
                                                                        deg);
  deg_final_kernel<<<(int)((BN + 255) / 256), 256, 0, stream>>>(deg, dis, inv);

  // ---- layer 1: x[.,256] @ W1 -> 16, aggregate, tanh ----
  mm1_kernel<<<4096, 256, 0, stream>>>(x, W1, bufA);
  hipMemsetAsync(bufB, 0, BN * 16 * sizeof(float), stream);
  edge_agg_kernel<16><<<dim3(NEDGES * 16 / 256, NB), 256, 0, stream>>>(
      ei, ew, dis, bufA, bufB);
  combine_kernel<16, true><<<(int)(BN * 16 / 256), 256, 0, stream>>>(
      bufB, bufA, inv, b1, bufB);

  // ---- layer 2: h1 @ W2 -> 16, aggregate, tanh ----
  mm_small_kernel<16><<<(int)(BN * 16 / 256), 256, 0, stream>>>(bufB, W2, bufA);
  hipMemsetAsync(bufB, 0, BN * 16 * sizeof(float), stream);
  edge_agg_kernel<16><<<dim3(NEDGES * 16 / 256, NB), 256, 0, stream>>>(
      ei, ew, dis, bufA, bufB);
  combine_kernel<16, true><<<(int)(BN * 16 / 256), 256, 0, stream>>>(
      bufB, bufA, inv, b2, bufB);

  // ---- layer 3: h2 @ W3 -> 32, aggregate, no tanh ----
  mm_small_kernel<32><<<(int)(BN * 32 / 256), 256, 0, stream>>>(bufB, W3, bufA);
  hipMemsetAsync(bufB, 0, BN * 32 * sizeof(float), stream);
  edge_agg_kernel<32><<<dim3(NEDGES * 32 / 256, NB), 256, 0, stream>>>(
      ei, ew, dis, bufA, bufB);
  combine_kernel<32, false><<<(int)(BN * 32 / 256), 256, 0, stream>>>(
      bufB, bufA, inv, b3, bufB);

  // ---- gather + MLP head ----
  fc_kernel<<<NB, 256, 0, stream>>>(bufB, pos, fcW1, fcb1, fcW2, fcb2, fcW3,
                                    fcb3, out);
}

// Round 6
// 1429.817 us; speedup vs baseline: 1.3811x; 1.3811x over previous
//
#include <hip/hip_runtime.h>

#define NNODES 20000
#define NEDGES 320000
#define NB 16
#define FIN 256
#define NP 5
#define NA 5

// ===========================================================================
// CSR build: counting-sort edges by dst (per batch), once per launch.
// Replaces 3x atomic-scatter aggregation (was ~1600us of 1975us).
// ===========================================================================

// count in-edges per dst node (int atomics, ~5.12M ops)
__global__ __launch_bounds__(256) void count_kernel(const int* __restrict__ ei,
                                                    int* __restrict__ cnt) {
  int b = blockIdx.y;
  int e = blockIdx.x * 256 + threadIdx.x;  // grid.x = NEDGES/256 exact
  int dst = ei[b * 2 * NEDGES + NEDGES + e];
  atomicAdd(&cnt[b * NNODES + dst], 1);
}

// per-batch exclusive scan of cnt -> rowptr (global offsets, +b*NEDGES)
__global__ __launch_bounds__(1024) void scan_kernel(const int* __restrict__ cnt,
                                                    int* __restrict__ rowptr) {
  int b = blockIdx.x;
  int tid = threadIdx.x;
  int lane = tid & 63, wid = tid >> 6;
  __shared__ int wsum[16];
  int carry = 0;
  for (int base = 0; base <= NNODES; base += 1024) {
    int i = base + tid;
    int v = (i < NNODES) ? cnt[b * NNODES + i] : 0;
    int x = v;
#pragma unroll
    for (int off = 1; off < 64; off <<= 1) {
      int y = __shfl_up(x, off);
      if (lane >= off) x += y;
    }
    if (lane == 63) wsum[wid] = x;
    __syncthreads();
    if (wid == 0) {
      int s = (lane < 16) ? wsum[lane] : 0;
#pragma unroll
      for (int off = 1; off < 16; off <<= 1) {
        int y = __shfl_up(s, off);
        if (lane >= off) s += y;
      }
      if (lane < 16) wsum[lane] = s;  // inclusive wave-sum scan
    }
    __syncthreads();
    int wpre = (wid == 0) ? 0 : wsum[wid - 1];
    int excl = x + wpre - v;  // exclusive prefix within chunk
    if (i <= NNODES) rowptr[b * (NNODES + 1) + i] = b * NEDGES + carry + excl;
    carry += wsum[15];
    __syncthreads();  // protect wsum before next iteration overwrites
  }
}

// scatter edges into CSR slots: csr[pos] = {src, bits(w)}
__global__ __launch_bounds__(256) void scatter_kernel(
    const int* __restrict__ ei, const float* __restrict__ ew,
    const int* __restrict__ rowptr, int* __restrict__ cur,
    int2* __restrict__ csr) {
  int b = blockIdx.y;
  int e = blockIdx.x * 256 + threadIdx.x;
  const int* eib = ei + b * 2 * NEDGES;
  int src = eib[e];
  int dst = eib[NEDGES + e];
  float w = ew[b * NEDGES + e];
  int pos = rowptr[b * (NNODES + 1) + dst] + atomicAdd(&cur[b * NNODES + dst], 1);
  csr[pos] = make_int2(src, __float_as_int(w));
}

// per-node: deg = 1 + sum(w over CSR range); dis = rsqrt(deg); inv = 1/deg
__global__ __launch_bounds__(256) void deg_kernel(const int* __restrict__ rowptr,
                                                  const int2* __restrict__ csr,
                                                  float* __restrict__ dis,
                                                  float* __restrict__ inv) {
  int b = blockIdx.y;
  int n = blockIdx.x * 256 + threadIdx.x;
  if (n >= NNODES) return;
  int start = rowptr[b * (NNODES + 1) + n];
  int end = rowptr[b * (NNODES + 1) + n + 1];
  float s = 1.0f;  // self-loop
  for (int k = start; k < end; ++k) s += __int_as_float(csr[k].y);
  dis[b * NNODES + n] = rsqrtf(s);
  inv[b * NNODES + n] = 1.0f / s;
}

// fold w *= dis[src] once (saves a random read per edge in each of 3 layers)
__global__ __launch_bounds__(256) void csrw_transform_kernel(
    const float* __restrict__ dis, int2* __restrict__ csr) {
  int b = blockIdx.y;
  int e = blockIdx.x * 256 + threadIdx.x;
  int k = b * NEDGES + e;
  int2 p = csr[k];
  float w = __int_as_float(p.y) * dis[b * NNODES + p.x];
  ((int*)csr)[2 * k + 1] = __float_as_int(w);
}

// ===========================================================================
// per-layer gather + fused combine:
// out[n][j] = maybe_tanh( dis[n]*sum_k csr_w[k]*xw[src_k][j]
//                         + xw[n][j]*inv[n] + bias[j] )
// F threads per node (F=16: 16 nodes/block; F=32: 8 nodes/block)
// ===========================================================================
template <int F, bool TANH>
__global__ __launch_bounds__(256) void gather_kernel(
    const int* __restrict__ rowptr, const int2* __restrict__ csr,
    const float* __restrict__ dis, const float* __restrict__ inv,
    const float* __restrict__ xw, const float* __restrict__ bias,
    float* __restrict__ out) {
  constexpr int NPB = 256 / F;
  int b = blockIdx.y;
  int n = blockIdx.x * NPB + threadIdx.x / F;  // grid.x exact divisor
  int j = threadIdx.x & (F - 1);
  long long bn = (long long)b * NNODES + n;
  int start = rowptr[b * (NNODES + 1) + n];
  int end = rowptr[b * (NNODES + 1) + n + 1];
  const float* xwb = xw + (long long)b * NNODES * F;
  float acc0 = 0.0f, acc1 = 0.0f;
  int k = start;
  for (; k + 2 <= end; k += 2) {
    int2 p0 = csr[k];
    int2 p1 = csr[k + 1];
    acc0 += __int_as_float(p0.y) * xwb[p0.x * F + j];
    acc1 += __int_as_float(p1.y) * xwb[p1.x * F + j];
  }
  if (k < end) {
    int2 p = csr[k];
    acc0 += __int_as_float(p.y) * xwb[p.x * F + j];
  }
  float self = xwb[n * F + j];
  float r = dis[bn] * (acc0 + acc1) + self * inv[bn] + bias[j];
  out[bn * F + j] = TANH ? tanhf(r) : r;
}

// ===========================================================================
// dense kernels (unchanged from baseline)
// ===========================================================================
__device__ __forceinline__ float wave_reduce16(const float p[16], int lane) {
  float v8[8];
  {
    const bool hi = lane & 1;
#pragma unroll
    for (int q = 0; q < 8; ++q) {
      float keep = hi ? p[2 * q + 1] : p[2 * q];
      float give = hi ? p[2 * q] : p[2 * q + 1];
      v8[q] = keep + __shfl_xor(give, 1);
    }
  }
  float v4[4];
  {
    const bool hi = (lane >> 1) & 1;
#pragma unroll
    for (int q = 0; q < 4; ++q) {
      float keep = hi ? v8[2 * q + 1] : v8[2 * q];
      float give = hi ? v8[2 * q] : v8[2 * q + 1];
      v4[q] = keep + __shfl_xor(give, 2);
    }
  }
  float v2[2];
  {
    const bool hi = (lane >> 2) & 1;
#pragma unroll
    for (int q = 0; q < 2; ++q) {
      float keep = hi ? v4[2 * q + 1] : v4[2 * q];
      float give = hi ? v4[2 * q] : v4[2 * q + 1];
      v2[q] = keep + __shfl_xor(give, 4);
    }
  }
  float v1;
  {
    const bool hi = (lane >> 3) & 1;
    float keep = hi ? v2[1] : v2[0];
    float give = hi ? v2[0] : v2[1];
    v1 = keep + __shfl_xor(give, 8);
  }
  v1 += __shfl_xor(v1, 16);
  v1 += __shfl_xor(v1, 32);
  return v1;
}

__global__ __launch_bounds__(256) void mm1_kernel(
    const float* __restrict__ x, const float* __restrict__ W1,
    float* __restrict__ xw) {
  const int lane = threadIdx.x & 63;
  const int wib = threadIdx.x >> 6;
  const int wave = blockIdx.x * 4 + wib;
  const int nwaves = gridDim.x * 4;

  float wreg[64];
  {
    const float4* W4 = (const float4*)(W1 + lane * 64);
#pragma unroll
    for (int q = 0; q < 16; ++q) {
      float4 v = W4[q];
      wreg[q * 4 + 0] = v.x;
      wreg[q * 4 + 1] = v.y;
      wreg[q * 4 + 2] = v.z;
      wreg[q * 4 + 3] = v.w;
    }
  }
  const int nrows = NB * NNODES;
  for (int row = wave; row < nrows; row += nwaves) {
    float4 xv = ((const float4*)x)[(long long)row * 64 + lane];
    float p[16];
#pragma unroll
    for (int j = 0; j < 16; ++j) {
      p[j] = xv.x * wreg[j] + xv.y * wreg[16 + j] + xv.z * wreg[32 + j] +
             xv.w * wreg[48 + j];
    }
    float v = wave_reduce16(p, lane);
    if (lane < 16) xw[(long long)row * 16 + lane] = v;
  }
}

template <int FOUT>
__global__ __launch_bounds__(256) void mm_small_kernel(
    const float* __restrict__ h, const float* __restrict__ W,
    float* __restrict__ out) {
  __shared__ float Ws[16 * FOUT];
  for (int t = threadIdx.x; t < 16 * FOUT; t += 256) Ws[t] = W[t];
  __syncthreads();
  int idx = blockIdx.x * 256 + threadIdx.x;
  if (idx >= NB * NNODES * FOUT) return;
  int row = idx / FOUT;
  int j = idx & (FOUT - 1);
  const float4* hr = (const float4*)(h + (long long)row * 16);
  float hv[16];
#pragma unroll
  for (int q = 0; q < 4; ++q) {
    float4 v = hr[q];
    hv[q * 4 + 0] = v.x;
    hv[q * 4 + 1] = v.y;
    hv[q * 4 + 2] = v.z;
    hv[q * 4 + 3] = v.w;
  }
  float acc = 0.0f;
#pragma unroll
  for (int k = 0; k < 16; ++k) acc += hv[k] * Ws[k * FOUT + j];
  out[idx] = acc;
}

__global__ __launch_bounds__(256) void fc_kernel(
    const float* __restrict__ emb, const int* __restrict__ pos,
    const float* __restrict__ fcW1, const float* __restrict__ fcb1,
    const float* __restrict__ fcW2, const float* __restrict__ fcb2,
    const float* __restrict__ fcW3, const float* __restrict__ fcb3,
    float* __restrict__ out) {
  int b = blockIdx.x;
  int tid = threadIdx.x;
  __shared__ float flat[160];
  __shared__ float hb[128];
  if (tid < 160) {
    int p = tid / 32, j = tid & 31;
    int pv = pos[b * NP + p];
    float v;
    if (pv == -1) {
      v = -3.0f;  // -DEPTH
    } else {
      int node = pv < 0 ? 0 : (pv > NNODES - 1 ? NNODES - 1 : pv);
      v = emb[((long long)b * NNODES + node) * 32 + j];
    }
    flat[tid] = v;
  }
  __syncthreads();
  float acc1 = 0.0f;
  if (tid < 128) {
    acc1 = fcb1[tid];
#pragma unroll 8
    for (int k = 0; k < 160; ++k) acc1 += flat[k] * fcW1[k * 128 + tid];
    acc1 = tanhf(acc1);
  }
  __syncthreads();
  if (tid < 128) hb[tid] = acc1;
  __syncthreads();
  float acc2 = 0.0f;
  if (tid < 128) {
    acc2 = fcb2[tid];
#pragma unroll 8
    for (int k = 0; k < 128; ++k) acc2 += hb[k] * fcW2[k * 128 + tid];
    acc2 = tanhf(acc2);
  }
  __syncthreads();
  if (tid < 128) flat[tid] = acc2;
  __syncthreads();
  if (tid < NA) {
    float acc = fcb3[tid];
#pragma unroll 8
    for (int k = 0; k < 128; ++k) acc += flat[k] * fcW3[k * NA + tid];
    out[b * NA + tid] = acc;
  }
}

// ===========================================================================
extern "C" void kernel_launch(void* const* d_in, const int* in_sizes, int n_in,
                              void* d_out, int out_size, void* d_ws,
                              size_t ws_size, hipStream_t stream) {
  const float* x = (const float*)d_in[0];
  const int* ei = (const int*)d_in[1];
  const float* ew = (const float*)d_in[2];
  const int* pos = (const int*)d_in[3];
  const float* W1 = (const float*)d_in[4];
  const float* b1 = (const float*)d_in[5];
  const float* W2 = (const float*)d_in[6];
  const float* b2 = (const float*)d_in[7];
  const float* W3 = (const float*)d_in[8];
  const float* b3 = (const float*)d_in[9];
  const float* fcW1 = (const float*)d_in[10];
  const float* fcb1 = (const float*)d_in[11];
  const float* fcW2 = (const float*)d_in[12];
  const float* fcb2 = (const float*)d_in[13];
  const float* fcW3 = (const float*)d_in[14];
  const float* fcb3 = (const float*)d_in[15];
  float* out = (float*)d_out;

  const long long BN = (long long)NB * NNODES;  // 320000
  // workspace layout (int-granular; csr 8B-aligned since prefix is even #ints)
  int* cnt = (int*)d_ws;                      // BN
  int* rowptr = cnt + BN;                     // NB*(NNODES+1) = 320016
  float* dis = (float*)(rowptr + NB * (NNODES + 1));  // BN
  float* inv = dis + BN;                      // BN
  int2* csr = (int2*)(inv + BN);              // NB*NEDGES int2 = 40.96 MB
  float* bufA = (float*)(csr + (long long)NB * NEDGES);  // BN*32
  float* bufB = bufA + BN * 32;               // BN*32
  // total: ~129.3 MB

  const dim3 egrid(NEDGES / 256, NB);  // 1250 x 16, exact

  // ---- CSR build (once; reused by all 3 layers) ----
  hipMemsetAsync(cnt, 0, BN * sizeof(int), stream);
  count_kernel<<<egrid, 256, 0, stream>>>(ei, cnt);
  scan_kernel<<<NB, 1024, 0, stream>>>(cnt, rowptr);
  hipMemsetAsync(cnt, 0, BN * sizeof(int), stream);  // reuse as cursor
  scatter_kernel<<<egrid, 256, 0, stream>>>(ei, ew, rowptr, cnt, csr);
  deg_kernel<<<dim3((NNODES + 255) / 256, NB), 256, 0, stream>>>(rowptr, csr,
                                                                 dis, inv);
  csrw_transform_kernel<<<egrid, 256, 0, stream>>>(dis, csr);

  // ---- layer 1: x @ W1 -> 16, gather+combine+tanh ----
  mm1_kernel<<<4096, 256, 0, stream>>>(x, W1, bufA);
  gather_kernel<16, true><<<dim3(NNODES / 16, NB), 256, 0, stream>>>(
      rowptr, csr, dis, inv, bufA, b1, bufB);

  // ---- layer 2 ----
  mm_small_kernel<16><<<(int)(BN * 16 / 256), 256, 0, stream>>>(bufB, W2, bufA);
  gather_kernel<16, true><<<dim3(NNODES / 16, NB), 256, 0, stream>>>(
      rowptr, csr, dis, inv, bufA, b2, bufB);

  // ---- layer 3 ----
  mm_small_kernel<32><<<(int)(BN * 32 / 256), 256, 0, stream>>>(bufB, W3, bufA);
  gather_kernel<32, false><<<dim3(NNODES / 8, NB), 256, 0, stream>>>(
      rowptr, csr, dis, inv, bufA, b3, bufB);

  // ---- gather + MLP head ----
  fc_kernel<<<NB, 256, 0, stream>>>(bufB, pos, fcW1, fcb1, fcW2, fcb2, fcW3,
                                    fcb3, out);
}